// Round 5
// baseline (210.671 us; speedup 1.0000x reference)
//
#include <hip/hip_runtime.h>

// Problem constants (B=2, S=2048, H=8, E=64).
// Harness passes f16 tensors upcast to FLOAT32 (in and out) — see header rule
// "bfloat16 -> __hip_bfloat16*, else float*". Internally we compute in f16
// (lossless re-narrowing of f16-origin data) with fp32 MFMA accumulation.
#define S_LEN 2048
#define NH    8
#define EMB   64
#define BM    64    // q rows per block (16 per wave)
#define BN    128   // kv tile length
#define PSTR  136   // padded LDS row stride (f16 elems; +8 => free 2-way aliasing only)
#define M_INIT  (-1.0e4f)  // finite, below any reachable score
#define EXP_CLAMP (-80.0f) // exp(-80)~2e-35: dead zero, no inf/NaN path

typedef _Float16 half8   __attribute__((ext_vector_type(8)));
typedef float    float4_t __attribute__((ext_vector_type(4)));
typedef float    float8_t __attribute__((ext_vector_type(8)));

// 8 consecutive f32 -> f16 fragment (32B vector load + v_cvt)
__device__ inline half8 cvt8(const float* p) {
    float8_t f = *reinterpret_cast<const float8_t*>(p);
    half8 h;
    #pragma unroll
    for (int j = 0; j < 8; ++j) h[j] = (_Float16)f[j];
    return h;
}

// ---------------------------------------------------------------------------
// Projection: Out[b,h,s,f] = f16(sum_e X[b,s,h,e]*W[f,e] + bias[f]) * scale.
// X f32 [B,S,H,E] row-major => flat rows r=(b*S+s)*H+h of 64. Out is [B,H,S,E];
// F16OUT=true -> f16 buffer (K,V), false -> f32 buffer holding f16-rounded
// values (Q -> d_out). scale=0.125 (exact pow2, commutes with f16 rounding).
// MFMA 16x16x32_f16: A-frag X[m=l15][e=ks*32+quad*8+j], B-frag W[f=l15][e=..].
// ---------------------------------------------------------------------------
template<bool F16OUT>
__global__ __launch_bounds__(256) void proj_one(
    const float* __restrict__ X, const float* __restrict__ W,
    const float* __restrict__ bias, void* __restrict__ OutP, float scale)
{
    const int tid  = threadIdx.x;
    const int lane = tid & 63;
    const int wave = tid >> 6;
    const int l15  = lane & 15;
    const int quad = lane >> 4;
    const int gwave = blockIdx.x * 4 + wave;   // 1024 waves, 2 row-tiles each

    half8 wf[4][2];
    #pragma unroll
    for (int ft = 0; ft < 4; ++ft)
        #pragma unroll
        for (int ks = 0; ks < 2; ++ks)
            wf[ft][ks] = cvt8(W + (ft * 16 + l15) * 64 + ks * 32 + quad * 8);
    float bv[4];
    #pragma unroll
    for (int ft = 0; ft < 4; ++ft) bv[ft] = bias[ft * 16 + l15];

    #pragma unroll
    for (int rt2 = 0; rt2 < 2; ++rt2) {
        const int rt = gwave * 2 + rt2;       // row-tile of 16
        const int arow = rt * 16 + l15;
        half8 xf[2];
        #pragma unroll
        for (int ks = 0; ks < 2; ++ks)
            xf[ks] = cvt8(X + (long)arow * 64 + ks * 32 + quad * 8);
        float4_t acc[4];
        #pragma unroll
        for (int ft = 0; ft < 4; ++ft) {
            acc[ft] = (float4_t){0.f, 0.f, 0.f, 0.f};
            #pragma unroll
            for (int ks = 0; ks < 2; ++ks)
                acc[ft] = __builtin_amdgcn_mfma_f32_16x16x32_f16(
                    xf[ks], wf[ft][ks], acc[ft], 0, 0, 0);
        }
        // C/D layout: col = lane&15 (f sub-index), row = quad*4 + r
        #pragma unroll
        for (int r = 0; r < 4; ++r) {
            const int row = rt * 16 + quad * 4 + r;     // (b*S+s)*H+h
            const int b = row >> 14;                    // S*H = 16384
            const int s = (row >> 3) & 2047;
            const int h = row & 7;
            const long orow = ((long)(b * NH + h) * S_LEN + s) * EMB;
            #pragma unroll
            for (int ft = 0; ft < 4; ++ft) {
                const _Float16 v =
                    (_Float16)(acc[ft][r] + bv[ft]) * (_Float16)scale;
                if (F16OUT) ((_Float16*)OutP)[orow + ft * 16 + l15] = v;
                else        ((float*)OutP)[orow + ft * 16 + l15] = (float)v;
            }
        }
    }
}

// ---------------------------------------------------------------------------
// Flash attention (non-causal, full softmax). One (bh, 64-row q tile) per
// block; 4 waves x 16 q rows. QO (f32) holds scaled Q on entry; each block
// reads only the 64 rows it later overwrites with O (read-before-write,
// rows disjoint across blocks, 256B cache-line aligned). K,V are f16.
// K fragments straight from global (L2-resident: 256+512 KB per head shared
// by 32 blocks). V staged transposed in LDS; P round-trips through LDS
// (C-layout -> A-layout).
// ---------------------------------------------------------------------------
__global__ __launch_bounds__(256) void attn_kernel(
    const _Float16* __restrict__ K, const _Float16* __restrict__ V,
    float* QO)
{
    __shared__ __align__(16) _Float16 Vt[64 * PSTR];     // V^T tile: [e][t]
    __shared__ __align__(16) _Float16 Pl[4][16 * PSTR];  // per-wave P: [m][t]

    const int tid  = threadIdx.x;
    const int lane = tid & 63;
    const int wave = tid >> 6;
    const int l15  = lane & 15;
    const int quad = lane >> 4;
    const int bh   = blockIdx.x >> 5;     // 32 q-tiles per head => L2 K/V reuse
    const int qt   = blockIdx.x & 31;
    const long base = (long)bh * S_LEN * EMB;
    const int qrow0 = qt * BM + wave * 16;

    // Q fragments: A[m=lane&15][k=ks*32+quad*8+j], f32 -> f16 (lossless here)
    half8 qf[2];
    #pragma unroll
    for (int ks = 0; ks < 2; ++ks)
        qf[ks] = cvt8(QO + base + (long)(qrow0 + l15) * EMB + ks * 32 + quad * 8);

    float4_t o[4];
    #pragma unroll
    for (int et = 0; et < 4; ++et) o[et] = (float4_t){0.f, 0.f, 0.f, 0.f};
    float m_run[4], l_run[4];
    #pragma unroll
    for (int r = 0; r < 4; ++r) { m_run[r] = M_INIT; l_run[r] = 0.f; }

    for (int kt = 0; kt < S_LEN / BN; ++kt) {
        if (kt) __syncthreads();          // protect Vt from previous-iter reads
        const int t0 = kt * BN;
        // stage V tile transposed: 128 rows x 64 cols, 8192 f16, 32/thread
        #pragma unroll
        for (int c = 0; c < 4; ++c) {
            const int chunk = c * 256 + tid;           // 1024 chunks of 8
            const int row = chunk >> 3, e0 = (chunk & 7) * 8;
            half8 v8 = *reinterpret_cast<const half8*>(
                V + base + (long)(t0 + row) * EMB + e0);
            #pragma unroll
            for (int j = 0; j < 8; ++j)
                Vt[(e0 + j) * PSTR + row] = v8[j];
        }
        __syncthreads();

        // S = Q K^T : 8 n-tiles of 16 cols, fp32 accumulate
        float4_t sacc[8];
        #pragma unroll
        for (int nt = 0; nt < 8; ++nt) sacc[nt] = (float4_t){0.f, 0.f, 0.f, 0.f};
        #pragma unroll
        for (int nt = 0; nt < 8; ++nt) {
            const long nrow = base + (long)(t0 + nt * 16 + l15) * EMB;
            #pragma unroll
            for (int ks = 0; ks < 2; ++ks) {
                half8 kf = *reinterpret_cast<const half8*>(
                    K + nrow + ks * 32 + quad * 8);
                sacc[nt] = __builtin_amdgcn_mfma_f32_16x16x32_f16(
                    qf[ks], kf, sacc[nt], 0, 0, 0);
            }
        }

        // online softmax; lane holds rows quad*4+r, cols l15 (+16*nt)
        float mx[4];
        #pragma unroll
        for (int r = 0; r < 4; ++r) {
            mx[r] = sacc[0][r];
            #pragma unroll
            for (int nt = 1; nt < 8; ++nt) mx[r] = fmaxf(mx[r], sacc[nt][r]);
        }
        #pragma unroll
        for (int off = 1; off < 16; off <<= 1)
            #pragma unroll
            for (int r = 0; r < 4; ++r)
                mx[r] = fmaxf(mx[r], __shfl_xor(mx[r], off));

        float alpha[4], rsum[4];
        #pragma unroll
        for (int r = 0; r < 4; ++r) {
            const float mn = fmaxf(m_run[r], mx[r]);
            alpha[r] = __expf(fmaxf(m_run[r] - mn, EXP_CLAMP));
            m_run[r] = mn;
            rsum[r] = 0.f;
        }
        _Float16* Pw = Pl[wave];
        #pragma unroll
        for (int nt = 0; nt < 8; ++nt)
            #pragma unroll
            for (int r = 0; r < 4; ++r) {
                const float p = __expf(fmaxf(sacc[nt][r] - m_run[r], EXP_CLAMP));
                rsum[r] += p;
                Pw[(quad * 4 + r) * PSTR + nt * 16 + l15] = (_Float16)p;
            }
        #pragma unroll
        for (int off = 1; off < 16; off <<= 1)
            #pragma unroll
            for (int r = 0; r < 4; ++r)
                rsum[r] += __shfl_xor(rsum[r], off);
        #pragma unroll
        for (int r = 0; r < 4; ++r)
            l_run[r] = l_run[r] * alpha[r] + rsum[r];
        #pragma unroll
        for (int et = 0; et < 4; ++et)
            #pragma unroll
            for (int r = 0; r < 4; ++r)
                o[et][r] *= alpha[r];
        __syncthreads();   // LDS writes drained before A-layout reads

        // O += P V : A-frag = P[m=l15][t=ts*32+quad*8+j], B-frag = Vt[e][t]
        #pragma unroll
        for (int ts = 0; ts < 4; ++ts) {
            half8 pf = *reinterpret_cast<const half8*>(
                &Pw[l15 * PSTR + ts * 32 + quad * 8]);
            #pragma unroll
            for (int et = 0; et < 4; ++et) {
                half8 vf = *reinterpret_cast<const half8*>(
                    &Vt[(et * 16 + l15) * PSTR + ts * 32 + quad * 8]);
                o[et] = __builtin_amdgcn_mfma_f32_16x16x32_f16(pf, vf, o[et], 0, 0, 0);
            }
        }
    }

    // epilogue: O / l, f16-round (matches ref's f16 output), store f32.
    // Overwrites exactly this block's own Q rows.
    #pragma unroll
    for (int r = 0; r < 4; ++r) {
        const float inv = 1.f / l_run[r];
        const int row = qrow0 + quad * 4 + r;
        #pragma unroll
        for (int et = 0; et < 4; ++et)
            QO[base + (long)row * EMB + et * 16 + l15] =
                (float)(_Float16)(o[et][r] * inv);
    }
}

// ---------------------------------------------------------------------------
// Buffer rotation (no d_ws; all targets guaranteed-size, stream-ordered):
//   proj Q: d_in[0](f32) -> d_out (f32, f16-rounded, pre-scaled 0.125)
//   proj K: d_in[1](f32) -> d_in[0] as f16 (4 MB into an 8 MB buffer)
//   proj V: d_in[2](f32) -> d_in[1] as f16
//   attn:   K=d_in[0](f16), V=d_in[1](f16), Q/O in d_out (f32)
// Harness restores d_in from pristine copies before every timed launch, so
// clobbering inputs is well-defined and identical on every call.
// ---------------------------------------------------------------------------
extern "C" void kernel_launch(void* const* d_in, const int* in_sizes, int n_in,
                              void* d_out, int out_size, void* d_ws, size_t ws_size,
                              hipStream_t stream) {
    const float* q_in = (const float*)d_in[0];
    const float* k_in = (const float*)d_in[1];
    const float* v_in = (const float*)d_in[2];
    const float* Wq   = (const float*)d_in[3];
    const float* bq   = (const float*)d_in[4];
    const float* Wk   = (const float*)d_in[5];
    const float* bk   = (const float*)d_in[6];
    const float* Wv   = (const float*)d_in[7];
    const float* bv   = (const float*)d_in[8];
    float* out = (float*)d_out;

    proj_one<false><<<256, 256, 0, stream>>>(q_in, Wq, bq, out, 0.125f);
    proj_one<true><<<256, 256, 0, stream>>>(k_in, Wk, bk, d_in[0], 1.0f);
    proj_one<true><<<256, 256, 0, stream>>>(v_in, Wv, bv, d_in[1], 1.0f);
    attn_kernel<<<512, 256, 0, stream>>>((const _Float16*)d_in[0],
                                         (const _Float16*)d_in[1], out);
}

// Round 6
// 181.534 us; speedup vs baseline: 1.1605x; 1.1605x over previous
//
#include <hip/hip_runtime.h>

// Problem constants (B=2, S=2048, H=8, E=64).
// Harness passes f16 tensors upcast to FLOAT32 (in and out). Internally f16
// compute (lossless re-narrowing of f16-origin data), fp32 MFMA accumulation.
#define S_LEN 2048
#define NH    8
#define EMB   64
#define BM    64    // q rows per block (16 per wave)
#define BN    128   // kv tile length
#define NSPLIT 2    // KV splits (flash-decoding): 16 bh x 32 qt x 2 = 1024 blocks
#define PSTR  136   // padded LDS row stride (f16 elems)
#define M_INIT  (-1.0e4f)
#define EXP_CLAMP (-80.0f)

typedef _Float16 half8   __attribute__((ext_vector_type(8)));
typedef float    float4_t __attribute__((ext_vector_type(4)));
typedef float    float8_t __attribute__((ext_vector_type(8)));

__device__ inline half8 cvt8(const float* p) {
    float8_t f = *reinterpret_cast<const float8_t*>(p);
    half8 h;
    #pragma unroll
    for (int j = 0; j < 8; ++j) h[j] = (_Float16)f[j];
    return h;
}

// ---------------------------------------------------------------------------
// Projection (unchanged from round 5, proven): Out[b,h,s,f] =
// f16(sum_e X*W + b) * scale, layout [B,H,S,E]. 3 stream-ordered launches.
// ---------------------------------------------------------------------------
template<bool F16OUT>
__global__ __launch_bounds__(256) void proj_one(
    const float* __restrict__ X, const float* __restrict__ W,
    const float* __restrict__ bias, void* __restrict__ OutP, float scale)
{
    const int tid  = threadIdx.x;
    const int lane = tid & 63;
    const int wave = tid >> 6;
    const int l15  = lane & 15;
    const int quad = lane >> 4;
    const int gwave = blockIdx.x * 4 + wave;

    half8 wf[4][2];
    #pragma unroll
    for (int ft = 0; ft < 4; ++ft)
        #pragma unroll
        for (int ks = 0; ks < 2; ++ks)
            wf[ft][ks] = cvt8(W + (ft * 16 + l15) * 64 + ks * 32 + quad * 8);
    float bv[4];
    #pragma unroll
    for (int ft = 0; ft < 4; ++ft) bv[ft] = bias[ft * 16 + l15];

    #pragma unroll
    for (int rt2 = 0; rt2 < 2; ++rt2) {
        const int rt = gwave * 2 + rt2;
        const int arow = rt * 16 + l15;
        half8 xf[2];
        #pragma unroll
        for (int ks = 0; ks < 2; ++ks)
            xf[ks] = cvt8(X + (long)arow * 64 + ks * 32 + quad * 8);
        float4_t acc[4];
        #pragma unroll
        for (int ft = 0; ft < 4; ++ft) {
            acc[ft] = (float4_t){0.f, 0.f, 0.f, 0.f};
            #pragma unroll
            for (int ks = 0; ks < 2; ++ks)
                acc[ft] = __builtin_amdgcn_mfma_f32_16x16x32_f16(
                    xf[ks], wf[ft][ks], acc[ft], 0, 0, 0);
        }
        #pragma unroll
        for (int r = 0; r < 4; ++r) {
            const int row = rt * 16 + quad * 4 + r;     // (b*S+s)*H+h
            const int b = row >> 14;
            const int s = (row >> 3) & 2047;
            const int h = row & 7;
            const long orow = ((long)(b * NH + h) * S_LEN + s) * EMB;
            #pragma unroll
            for (int ft = 0; ft < 4; ++ft) {
                const _Float16 v =
                    (_Float16)(acc[ft][r] + bv[ft]) * (_Float16)scale;
                if (F16OUT) ((_Float16*)OutP)[orow + ft * 16 + l15] = v;
                else        ((float*)OutP)[orow + ft * 16 + l15] = (float)v;
            }
        }
    }
}

// ---------------------------------------------------------------------------
// Pass 1: flash attention partials, KV-split=2. Block = (bh, 64-row q tile,
// split); 4 waves x 16 q rows; 8 K-tiles of BN=128 per block. Inner loop is
// byte-identical to the round-5 proven kernel. Epilogue emits normalized
// partial O-hat (f16) + per-row (m, l) stats instead of the final output.
// ---------------------------------------------------------------------------
__global__ __launch_bounds__(256) void attn_part(
    const _Float16* __restrict__ K, const _Float16* __restrict__ V,
    const float* __restrict__ Qbuf, _Float16* __restrict__ part,
    float* __restrict__ stats)
{
    __shared__ __align__(16) _Float16 Vt[64 * PSTR];     // V^T tile: [e][t]
    __shared__ __align__(16) _Float16 Pl[4][16 * PSTR];  // per-wave P: [m][t]

    const int tid  = threadIdx.x;
    const int lane = tid & 63;
    const int wave = tid >> 6;
    const int l15  = lane & 15;
    const int quad = lane >> 4;
    const int bx   = blockIdx.x;          // bh*64 + qt*2 + sp
    const int bh   = bx >> 6;
    const int qt   = (bx >> 1) & 31;
    const int sp   = bx & 1;
    const long base = (long)bh * S_LEN * EMB;
    const int qrow0 = qt * BM + wave * 16;

    half8 qf[2];
    #pragma unroll
    for (int ks = 0; ks < 2; ++ks)
        qf[ks] = cvt8(Qbuf + base + (long)(qrow0 + l15) * EMB + ks * 32 + quad * 8);

    float4_t o[4];
    #pragma unroll
    for (int et = 0; et < 4; ++et) o[et] = (float4_t){0.f, 0.f, 0.f, 0.f};
    float m_run[4], l_run[4];
    #pragma unroll
    for (int r = 0; r < 4; ++r) { m_run[r] = M_INIT; l_run[r] = 0.f; }

    const int kt0 = sp * (S_LEN / BN / NSPLIT);          // 8 tiles per split
    for (int kti = 0; kti < S_LEN / BN / NSPLIT; ++kti) {
        const int kt = kt0 + kti;
        if (kti) __syncthreads();
        const int t0 = kt * BN;
        #pragma unroll
        for (int c = 0; c < 4; ++c) {
            const int chunk = c * 256 + tid;
            const int row = chunk >> 3, e0 = (chunk & 7) * 8;
            half8 v8 = *reinterpret_cast<const half8*>(
                V + base + (long)(t0 + row) * EMB + e0);
            #pragma unroll
            for (int j = 0; j < 8; ++j)
                Vt[(e0 + j) * PSTR + row] = v8[j];
        }
        __syncthreads();

        float4_t sacc[8];
        #pragma unroll
        for (int nt = 0; nt < 8; ++nt) sacc[nt] = (float4_t){0.f, 0.f, 0.f, 0.f};
        #pragma unroll
        for (int nt = 0; nt < 8; ++nt) {
            const long nrow = base + (long)(t0 + nt * 16 + l15) * EMB;
            #pragma unroll
            for (int ks = 0; ks < 2; ++ks) {
                half8 kf = *reinterpret_cast<const half8*>(
                    K + nrow + ks * 32 + quad * 8);
                sacc[nt] = __builtin_amdgcn_mfma_f32_16x16x32_f16(
                    qf[ks], kf, sacc[nt], 0, 0, 0);
            }
        }

        float mx[4];
        #pragma unroll
        for (int r = 0; r < 4; ++r) {
            mx[r] = sacc[0][r];
            #pragma unroll
            for (int nt = 1; nt < 8; ++nt) mx[r] = fmaxf(mx[r], sacc[nt][r]);
        }
        #pragma unroll
        for (int off = 1; off < 16; off <<= 1)
            #pragma unroll
            for (int r = 0; r < 4; ++r)
                mx[r] = fmaxf(mx[r], __shfl_xor(mx[r], off));

        float alpha[4], rsum[4];
        #pragma unroll
        for (int r = 0; r < 4; ++r) {
            const float mn = fmaxf(m_run[r], mx[r]);
            alpha[r] = __expf(fmaxf(m_run[r] - mn, EXP_CLAMP));
            m_run[r] = mn;
            rsum[r] = 0.f;
        }
        _Float16* Pw = Pl[wave];
        #pragma unroll
        for (int nt = 0; nt < 8; ++nt)
            #pragma unroll
            for (int r = 0; r < 4; ++r) {
                const float p = __expf(fmaxf(sacc[nt][r] - m_run[r], EXP_CLAMP));
                rsum[r] += p;
                Pw[(quad * 4 + r) * PSTR + nt * 16 + l15] = (_Float16)p;
            }
        #pragma unroll
        for (int off = 1; off < 16; off <<= 1)
            #pragma unroll
            for (int r = 0; r < 4; ++r)
                rsum[r] += __shfl_xor(rsum[r], off);
        #pragma unroll
        for (int r = 0; r < 4; ++r)
            l_run[r] = l_run[r] * alpha[r] + rsum[r];
        #pragma unroll
        for (int et = 0; et < 4; ++et)
            #pragma unroll
            for (int r = 0; r < 4; ++r)
                o[et][r] *= alpha[r];
        __syncthreads();

        #pragma unroll
        for (int ts = 0; ts < 4; ++ts) {
            half8 pf = *reinterpret_cast<const half8*>(
                &Pw[l15 * PSTR + ts * 32 + quad * 8]);
            #pragma unroll
            for (int et = 0; et < 4; ++et) {
                half8 vf = *reinterpret_cast<const half8*>(
                    &Vt[(et * 16 + l15) * PSTR + ts * 32 + quad * 8]);
                o[et] = __builtin_amdgcn_mfma_f32_16x16x32_f16(pf, vf, o[et], 0, 0, 0);
            }
        }
    }

    // epilogue: normalized partial O-hat (f16) + (m,l) stats.
    // part layout: [sp][bh][row][e]; stats: m at [sp*32768 + R], l at +65536.
    #pragma unroll
    for (int r = 0; r < 4; ++r) {
        const float inv = 1.f / l_run[r];
        const int row = qrow0 + quad * 4 + r;            // 0..2047 within head
        const int R = bh * S_LEN + row;                  // 0..32767 global row
        const long prow = ((long)sp * 32768 + R) * EMB;
        #pragma unroll
        for (int et = 0; et < 4; ++et)
            part[prow + et * 16 + l15] = (_Float16)(o[et][r] * inv);
        if (l15 == 0) {                                  // m,l uniform across l15
            stats[sp * 32768 + R] = m_run[r];
            stats[2 * 32768 + sp * 32768 + R] = l_run[r];
        }
    }
}

// ---------------------------------------------------------------------------
// Pass 2: combine the 2 partials. Each thread: one row x 16 cols.
// O = (w0*Ohat0 + w1*Ohat1), w_i = l_i*exp(m_i-M) normalized. f16-round, f32 store.
// ---------------------------------------------------------------------------
__global__ __launch_bounds__(256) void attn_combine(
    const _Float16* __restrict__ part, const float* __restrict__ stats,
    float* __restrict__ out)
{
    const int gid = blockIdx.x * 256 + threadIdx.x;      // 131072 threads
    const int R  = gid >> 2;                             // 0..32767
    const int c0 = (gid & 3) * 16;
    const float m0 = stats[R],           m1 = stats[32768 + R];
    const float l0 = stats[2*32768 + R], l1 = stats[3*32768 + R];
    const float M  = fmaxf(m0, m1);
    float w0 = l0 * __expf(fmaxf(m0 - M, EXP_CLAMP));
    float w1 = l1 * __expf(fmaxf(m1 - M, EXP_CLAMP));
    const float rinv = 1.f / (w0 + w1);
    w0 *= rinv; w1 *= rinv;
    const long i0 = (long)R * EMB + c0;
    const long i1 = i0 + (long)32768 * EMB;
    #pragma unroll
    for (int h = 0; h < 2; ++h) {
        half8 a = *reinterpret_cast<const half8*>(part + i0 + h * 8);
        half8 b = *reinterpret_cast<const half8*>(part + i1 + h * 8);
        #pragma unroll
        for (int j = 0; j < 8; ++j)
            out[i0 + h * 8 + j] =
                (float)(_Float16)(w0 * (float)a[j] + w1 * (float)b[j]);
    }
}

// ---------------------------------------------------------------------------
// Buffer plan (no d_ws; all guaranteed-size, stream-ordered):
//   proj Q: d_in[0](f32) -> d_out (f32, f16-rounded, pre-scaled 0.125)
//   proj K: d_in[1](f32) -> d_in[0][0..4MB) as f16
//   proj V: d_in[2](f32) -> d_in[1][0..4MB) as f16
//   pass1:  K=d_in[0], V=d_in[1], Q=d_out (read-only now);
//           partials -> d_in[2] (exactly 8MB), stats -> d_in[0]+4MB (512KB)
//   pass2:  combine -> d_out (Q dead after pass1)
// ---------------------------------------------------------------------------
extern "C" void kernel_launch(void* const* d_in, const int* in_sizes, int n_in,
                              void* d_out, int out_size, void* d_ws, size_t ws_size,
                              hipStream_t stream) {
    const float* q_in = (const float*)d_in[0];
    const float* k_in = (const float*)d_in[1];
    const float* v_in = (const float*)d_in[2];
    const float* Wq   = (const float*)d_in[3];
    const float* bq   = (const float*)d_in[4];
    const float* Wk   = (const float*)d_in[5];
    const float* bk   = (const float*)d_in[6];
    const float* Wv   = (const float*)d_in[7];
    const float* bv   = (const float*)d_in[8];
    float* out = (float*)d_out;

    _Float16* Kf16  = (_Float16*)d_in[0];
    _Float16* Vf16  = (_Float16*)d_in[1];
    _Float16* partb = (_Float16*)d_in[2];
    float*    stats = (float*)((char*)d_in[0] + (4u << 20));

    proj_one<false><<<256, 256, 0, stream>>>(q_in, Wq, bq, out, 0.125f);
    proj_one<true><<<256, 256, 0, stream>>>(k_in, Wk, bk, (void*)Kf16, 1.0f);
    proj_one<true><<<256, 256, 0, stream>>>(v_in, Wv, bv, (void*)Vf16, 1.0f);
    attn_part<<<1024, 256, 0, stream>>>(Kf16, Vf16, out, partb, stats);
    attn_combine<<<512, 256, 0, stream>>>(partb, stats, out);
}